// Round 15
// baseline (912.786 us; speedup 1.0000x reference)
//
#include <hip/hip_runtime.h>
#include <hip/hip_bf16.h>
#include <stdint.h>

#define DEVI __device__ __forceinline__

typedef __attribute__((ext_vector_type(8))) __bf16 bf16x8;
typedef __attribute__((ext_vector_type(4))) float f32x4;

DEVI unsigned short f2b(float f) {
  union { float f; unsigned int u; } x; x.f = f;
  unsigned int u = x.u;
  return (unsigned short)((u + 0x7fffu + ((u >> 16) & 1u)) >> 16);
}

DEVI float b2f(unsigned short b) {
  union { unsigned int u; float f; } x; x.u = (unsigned int)b << 16;
  return x.f;
}

// ---- feat: fp32 [b][P][D] -> bf16 [b][P][D] AND bf16 [b][D][P] in one read ----
__global__ void feat_cvt_tr_kernel(const float* __restrict__ in,
                                   unsigned short* __restrict__ outN,
                                   unsigned short* __restrict__ outT,
                                   int P, int D) {
  __shared__ unsigned short tile[32][33];
  int b = blockIdx.z;
  int d0 = blockIdx.x * 32, p0 = blockIdx.y * 32;
  const float* src = in + (long)b * P * D;
  unsigned short* dstN = outN + (long)b * P * D;
  unsigned short* dstT = outT + (long)b * D * P;
  int tx = threadIdx.x & 31, ty = threadIdx.x >> 5; // 32 x 8
  for (int i = 0; i < 32; i += 8) {
    unsigned short v = f2b(src[(long)(p0 + ty + i) * D + d0 + tx]);
    tile[ty + i][tx] = v;
    dstN[(long)(p0 + ty + i) * D + d0 + tx] = v;
  }
  __syncthreads();
  for (int i = 0; i < 32; i += 8)
    dstT[(long)(d0 + ty + i) * P + p0 + tx] = tile[tx][ty + i];
}

// ---- both weight transposes in one dispatch: z=0 -> Wq, z=1 -> Wk ----
__global__ void wtr2_kernel(const float* __restrict__ Wq,
                            const float* __restrict__ Wk,
                            unsigned short* __restrict__ WqT,
                            unsigned short* __restrict__ WkT, int D) {
  __shared__ unsigned short tile[32][33];
  const float* src = blockIdx.z ? Wk : Wq;
  unsigned short* dst = blockIdx.z ? WkT : WqT;
  int d0 = blockIdx.x * 32, p0 = blockIdx.y * 32;
  int tx = threadIdx.x & 31, ty = threadIdx.x >> 5; // 32 x 8
  for (int i = 0; i < 32; i += 8)
    tile[ty + i][tx] = f2b(src[(long)(p0 + ty + i) * D + d0 + tx]);
  __syncthreads();
  for (int i = 0; i < 32; i += 8)
    dst[(long)(d0 + ty + i) * D + p0 + tx] = tile[tx][ty + i];
}

// ---- out[row] = sum_j A_bf16[row][j] * v_f32[j]  (one wave per row) ----
__global__ void rowdot_bf16_kernel(const unsigned short* __restrict__ A,
                                   const float* __restrict__ v,
                                   float* __restrict__ out, int D) {
  long row = (long)blockIdx.x * 4 + (threadIdx.x >> 6);
  int lane = threadIdx.x & 63;
  const ushort4* ar = (const ushort4*)(A + row * D);
  const float4* vv = (const float4*)v;
  float s = 0.f;
  for (int j = lane; j < D / 4; j += 64) {
    ushort4 a = ar[j];
    float4 g = vv[j];
    s += b2f(a.x) * g.x + b2f(a.y) * g.y + b2f(a.z) * g.z + b2f(a.w) * g.w;
  }
#pragma unroll
  for (int o = 32; o > 0; o >>= 1) s += __shfl_xor(s, o, 64);
  if (lane == 0) out[row] = s;
}

// ---------------- async global->LDS 16B ----------------
DEVI void gll16(const void* g, void* l) {
  __builtin_amdgcn_global_load_lds(
      (const __attribute__((address_space(1))) unsigned int*)g,
      (__attribute__((address_space(3))) unsigned int*)l, 16, 0, 0);
}

// ---------------- generic NT GEMM: C = (A * B^T + colbias) * scale ----------------
// A [M][K] row-major (bf16, or fp32 when A_F32=1), B [N][K] bf16 row-major.
// BK=64. Tile = (WM*ACCM*16) x (WN*ACCN*16); WM*WN waves (256 thr);
// mfma 16x16x32 bf16, 2 sub-k per iter. LDS stripe [16][64] bf16 with
// per-16B-slot XOR swizzle (slot ^= row&7) applied on BOTH the staging
// source column (LDS dest linear, rule 21) and the ds_read address ->
// conflict-free (round-11 verified: SQ_LDS_BANK_CONFLICT = 0).
// A_F32=1: A staged via registers (2x dwordx4 fp32 load + RNE cvt +
// ds_write_b64 pair) into the IDENTICAL LDS layout -> numerics unchanged;
// eliminates the separate text fp32->bf16 conversion pass.
// Single-buffered: stage -> sync -> compute -> sync (round-11 proven).
// WAVES_EU = 4 ALWAYS for acc[4][4] (5 spills accumulators, round-13:
// 1.45 GB scratch writes; dbuf regressed round-12: 64KB LDS halves residency).
// BATCH_X: batch folded into blockIdx.x low 3 bits (XCD affinity for B-panel).
template<int OUT_BF16, int HAS_BIAS, int BATCH_X,
         int WM, int WN, int ACCM, int ACCN, int WAVES_EU, int A_F32>
__global__ __launch_bounds__(256, WAVES_EU) void gemm_nt_kernel(
    const void* __restrict__ Av,
    const unsigned short* __restrict__ B,
    void* __restrict__ Cv,
    const float* __restrict__ bias,
    float scale, int M, int N, int K,
    long sA, long sB, long sC, long sBias) {
  constexpr int NW = WM * WN;        // waves per block (4)
  constexpr int SA = WM * ACCM;      // A 16-row stripes per tile
  constexpr int SB = WN * ACCN;      // B 16-row stripes per tile
  constexpr int CA2 = SA * 2 / NW;   // A staging issues per wave
  constexpr int CB2 = SB * 2 / NW;
  static_assert(CA2 * NW == SA * 2 && CB2 * NW == SB * 2, "issue divisibility");

  __shared__ unsigned short As[SA * 1024];  // stripe = 1024 ushorts = 2 KB
  __shared__ unsigned short Bs[SB * 1024];

  const int tid = threadIdx.x;
  const int lane = tid & 63;
  const int wid = tid >> 6;
  const int wm = wid / WN;
  const int wn = wid % WN;

  int bx = blockIdx.x;
  int b;
  if (BATCH_X) { b = bx & 7; bx >>= 3; } else { b = blockIdx.z; }
  const int n0 = bx * (SB * 16);
  const int m0 = blockIdx.y * (SA * 16);

  const unsigned short* Ab = A_F32 ? nullptr : (const unsigned short*)Av + (long)b * sA;
  const float* Afb = A_F32 ? (const float*)Av + (long)b * sA : nullptr;
  const unsigned short* Bb = B + (long)b * sB;
  const float* biasb = HAS_BIAS ? bias + (long)b * sBias : nullptr;

  // staging: issue (j,i) covers rows j*16+i*8..+7 of a stripe, 64 K-cols.
  // lane -> row offset lane>>3, source col slot (lane&7)^(lane>>3) (x8 elems)
  const int r8 = lane >> 3;
  const int csw = ((lane & 7) ^ r8) * 8;  // pre-swizzled source col (elements)

  auto stage = [&](int k0) {
#pragma unroll
    for (int t = 0; t < CA2; ++t) {
      const int a = wid * CA2 + t, j = a >> 1, i = a & 1;
      if constexpr (A_F32) {
        const float* src = Afb + (long)(m0 + j * 16 + i * 8 + r8) * K + k0 + csw;
        float4 v0 = *reinterpret_cast<const float4*>(src);
        float4 v1 = *reinterpret_cast<const float4*>(src + 4);
        ushort4 o0 = { f2b(v0.x), f2b(v0.y), f2b(v0.z), f2b(v0.w) };
        ushort4 o1 = { f2b(v1.x), f2b(v1.y), f2b(v1.z), f2b(v1.w) };
        unsigned short* dst = As + j * 1024 + i * 512 + lane * 8;
        *reinterpret_cast<ushort4*>(dst) = o0;
        *reinterpret_cast<ushort4*>(dst + 4) = o1;
      } else {
        gll16(Ab + (long)(m0 + j * 16 + i * 8 + r8) * K + k0 + csw,
              (void*)(As + j * 1024 + i * 512));
      }
    }
#pragma unroll
    for (int t = 0; t < CB2; ++t) {
      const int a = wid * CB2 + t, j = a >> 1, i = a & 1;
      gll16(Bb + (long)(n0 + j * 16 + i * 8 + r8) * K + k0 + csw,
            (void*)(Bs + j * 1024 + i * 512));
    }
  };

  f32x4 acc[ACCM][ACCN];
#pragma unroll
  for (int m = 0; m < ACCM; ++m)
#pragma unroll
    for (int n = 0; n < ACCN; ++n) acc[m][n] = (f32x4){0.f, 0.f, 0.f, 0.f};

  const int lrow = lane & 15;     // fragment row within 16-row stripe
  const int x7 = lane & 7;        // row&7 for the read-side XOR
  const int g = lane >> 4;        // k-group 0..3
  const int so0 = ((g) ^ x7) * 8;       // sub-k 0 swizzled ushort offset
  const int so1 = ((4 + g) ^ x7) * 8;   // sub-k 1
  const int wmA = wm * ACCM * 16;
  const int wnB = wn * ACCN * 16;

  for (int k0 = 0; k0 < K; k0 += 64) {
    stage(k0);
    __syncthreads();

#pragma unroll
    for (int s = 0; s < 2; ++s) {
      const int so = s ? so1 : so0;
      bf16x8 af[ACCM], bfr[ACCN];
#pragma unroll
      for (int m = 0; m < ACCM; ++m)
        af[m] = *reinterpret_cast<const bf16x8*>(
            &As[(wmA + m * 16 + lrow) * 64 + so]);
#pragma unroll
      for (int n = 0; n < ACCN; ++n)
        bfr[n] = *reinterpret_cast<const bf16x8*>(
            &Bs[(wnB + n * 16 + lrow) * 64 + so]);
#pragma unroll
      for (int m = 0; m < ACCM; ++m)
#pragma unroll
        for (int n = 0; n < ACCN; ++n)
          acc[m][n] = __builtin_amdgcn_mfma_f32_16x16x32_bf16(af[m], bfr[n], acc[m][n], 0, 0, 0);
    }

    __syncthreads();
  }

  const int crow = (lane >> 4) * 4;
  const int ccol = lane & 15;
#pragma unroll
  for (int m = 0; m < ACCM; ++m) {
#pragma unroll
    for (int n = 0; n < ACCN; ++n) {
      const int gc = n0 + wn * ACCN * 16 + n * 16 + ccol;
      float bv = HAS_BIAS ? biasb[gc] : 0.f;
#pragma unroll
      for (int r = 0; r < 4; ++r) {
        const int gr = m0 + wm * ACCM * 16 + m * 16 + crow + r;
        float v = (acc[m][n][r] + bv) * scale;
        long off = (long)b * sC + (long)gr * N + gc;
        if (OUT_BF16)
          ((unsigned short*)Cv)[off] = f2b(v);
        else
          ((float*)Cv)[off] = v;
      }
    }
  }
}

// ---------------- row softmax over P=576, fp32 in -> bf16 out ----------------
__global__ void softmax_kernel(const float* __restrict__ s,
                               unsigned short* __restrict__ attn) {
  const int P = 576;
  long row = (long)blockIdx.x * 4 + (threadIdx.x >> 6);
  int lane = threadIdx.x & 63;
  const float* sr = s + row * P;
  unsigned short* ar = attn + row * P;
  float v[9];
  float mx = -3.0e38f;
#pragma unroll
  for (int j = 0; j < 9; ++j) {
    v[j] = sr[j * 64 + lane];
    mx = fmaxf(mx, v[j]);
  }
#pragma unroll
  for (int o = 32; o > 0; o >>= 1) mx = fmaxf(mx, __shfl_xor(mx, o, 64));
  float sum = 0.f;
#pragma unroll
  for (int j = 0; j < 9; ++j) {
    v[j] = __expf(v[j] - mx);
    sum += v[j];
  }
#pragma unroll
  for (int o = 32; o > 0; o >>= 1) sum += __shfl_xor(sum, o, 64);
  float inv = 1.0f / sum;
#pragma unroll
  for (int j = 0; j < 9; ++j) ar[j * 64 + lane] = f2b(v[j] * inv);
}

extern "C" void kernel_launch(void* const* d_in, const int* in_sizes, int n_in,
                              void* d_out, int out_size, void* d_ws, size_t ws_size,
                              hipStream_t stream) {
  const float* text = (const float*)d_in[0];
  const float* feat = (const float*)d_in[1];
  const float* Wq = (const float*)d_in[2];
  const float* bq = (const float*)d_in[3];
  const float* Wk = (const float*)d_in[4];
  const float* bk = (const float*)d_in[5];
  (void)bk;  // bk's contribution to scores is constant over p -> softmax-invariant

  const int B = 8, T = 2048, P = 576, D = 4096;

  char* ws = (char*)d_ws;
  unsigned short* feat_b = (unsigned short*)(ws + 134217728);  //  37,748,736
  unsigned short* fT_b   = (unsigned short*)(ws + 171966464);  //  37,748,736
  unsigned short* WqT_b  = (unsigned short*)(ws + 209715200);  //  33,554,432
  unsigned short* WkT_b  = (unsigned short*)(ws + 243269632);  //  33,554,432
  unsigned short* attn_b = (unsigned short*)(ws + 276824064);  //  18,874,368
  float* u               = (float*)(ws + 295698432);           //      16,384
  float* c               = (float*)(ws + 295714816);           //      18,432
  float* scores          = (float*)(ws + 209715200);           // alias over WqT/WkT (dead after W2T)
  unsigned short* W2T_b  = (unsigned short*)d_out;                     // head of d_out
  unsigned short* KW_b   = (unsigned short*)((char*)d_out + 67108864); // +64 MB

  dim3 blk(256);
  feat_cvt_tr_kernel<<<dim3(D / 32, P / 32, B), blk, 0, stream>>>(feat, feat_b, fT_b, P, D);
  wtr2_kernel<<<dim3(D / 32, D / 32, 2), blk, 0, stream>>>(Wq, Wk, WqT_b, WkT_b, D);
  // bias pre-pass (bf16 row-dots): u[y] = WkT[y,:].bq ; c[bp] = feat_b[bp,:].u
  rowdot_bf16_kernel<<<D / 4, blk, 0, stream>>>(WkT_b, bq, u, D);
  rowdot_bf16_kernel<<<(B * P) / 4, blk, 0, stream>>>(feat_b, u, c, D);

  // W2T[x][y] = sum_d Wq[d,x] Wk[d,y] : 128x128, BK=64 (round-11/14 proven)
  gemm_nt_kernel<1, 0, 0, 2, 2, 4, 4, 4, 0><<<dim3(32, 32, 1), blk, 0, stream>>>(
      WqT_b, WkT_b, W2T_b, nullptr, 1.0f, D, D, D, 0, 0, 0, 0);
  // KW[bp][x] = sum_y feat[bp,y] W2T[x,y] : 128x128, BK=64
  gemm_nt_kernel<1, 0, 0, 2, 2, 4, 4, 4, 0><<<dim3(32, 36, 1), blk, 0, stream>>>(
      feat_b, W2T_b, KW_b, nullptr, 1.0f, B * P, D, D, 0, 0, 0, 0);
  // scores[b][t][p] = (text[b,t,:].KW[b,p,:] + c[b,p]) / 64 : 256x64 tiles,
  // A staged directly from fp32 text (reg path, RNE cvt — no cvt pre-pass),
  // exact N fit, batch->XCD
  gemm_nt_kernel<0, 1, 1, 2, 2, 8, 2, 4, 1><<<dim3(72, 8), blk, 0, stream>>>(
      text, KW_b, scores, c, 1.0f / 64.0f, T, P, D,
      (long)T * D, (long)P * D, (long)T * P, P);
  softmax_kernel<<<(B * T) / 4, blk, 0, stream>>>(scores, attn_b);
  // attended = attn * featT^T : 128x128 tiles, K=576, batch->XCD
  gemm_nt_kernel<0, 0, 1, 2, 2, 4, 4, 4, 0><<<dim3(256, 16), blk, 0, stream>>>(
      attn_b, fT_b, (float*)d_out, nullptr, 1.0f, T, D, P,
      (long)T * P, (long)D * P, (long)T * D, 0);
}

// Round 16
// 717.667 us; speedup vs baseline: 1.2719x; 1.2719x over previous
//
#include <hip/hip_runtime.h>
#include <hip/hip_bf16.h>
#include <stdint.h>

#define DEVI __device__ __forceinline__

typedef __attribute__((ext_vector_type(8))) __bf16 bf16x8;
typedef __attribute__((ext_vector_type(4))) float f32x4;

DEVI unsigned short f2b(float f) {
  union { float f; unsigned int u; } x; x.f = f;
  unsigned int u = x.u;
  return (unsigned short)((u + 0x7fffu + ((u >> 16) & 1u)) >> 16);
}

DEVI float b2f(unsigned short b) {
  union { unsigned int u; float f; } x; x.u = (unsigned int)b << 16;
  return x.f;
}

// ---------------- fp32 -> bf16 convert (vectorized) ----------------
__global__ void cvt_kernel(const float* __restrict__ in,
                           unsigned short* __restrict__ out, long n4) {
  long i = (long)blockIdx.x * blockDim.x + threadIdx.x;
  long stride = (long)gridDim.x * blockDim.x;
  for (; i < n4; i += stride) {
    float4 v = reinterpret_cast<const float4*>(in)[i];
    ushort4 o;
    o.x = f2b(v.x); o.y = f2b(v.y); o.z = f2b(v.z); o.w = f2b(v.w);
    reinterpret_cast<ushort4*>(out)[i] = o;
  }
}

// ---- feat: fp32 [b][P][D] -> bf16 [b][P][D] AND bf16 [b][D][P] in one read ----
__global__ void feat_cvt_tr_kernel(const float* __restrict__ in,
                                   unsigned short* __restrict__ outN,
                                   unsigned short* __restrict__ outT,
                                   int P, int D) {
  __shared__ unsigned short tile[32][33];
  int b = blockIdx.z;
  int d0 = blockIdx.x * 32, p0 = blockIdx.y * 32;
  const float* src = in + (long)b * P * D;
  unsigned short* dstN = outN + (long)b * P * D;
  unsigned short* dstT = outT + (long)b * D * P;
  int tx = threadIdx.x & 31, ty = threadIdx.x >> 5; // 32 x 8
  for (int i = 0; i < 32; i += 8) {
    unsigned short v = f2b(src[(long)(p0 + ty + i) * D + d0 + tx]);
    tile[ty + i][tx] = v;
    dstN[(long)(p0 + ty + i) * D + d0 + tx] = v;
  }
  __syncthreads();
  for (int i = 0; i < 32; i += 8)
    dstT[(long)(d0 + ty + i) * P + p0 + tx] = tile[tx][ty + i];
}

// ---- both weight transposes in one dispatch: z=0 -> Wq, z=1 -> Wk ----
__global__ void wtr2_kernel(const float* __restrict__ Wq,
                            const float* __restrict__ Wk,
                            unsigned short* __restrict__ WqT,
                            unsigned short* __restrict__ WkT, int D) {
  __shared__ unsigned short tile[32][33];
  const float* src = blockIdx.z ? Wk : Wq;
  unsigned short* dst = blockIdx.z ? WkT : WqT;
  int d0 = blockIdx.x * 32, p0 = blockIdx.y * 32;
  int tx = threadIdx.x & 31, ty = threadIdx.x >> 5; // 32 x 8
  for (int i = 0; i < 32; i += 8)
    tile[ty + i][tx] = f2b(src[(long)(p0 + ty + i) * D + d0 + tx]);
  __syncthreads();
  for (int i = 0; i < 32; i += 8)
    dst[(long)(d0 + ty + i) * D + p0 + tx] = tile[tx][ty + i];
}

// ---- out[row] = sum_j A_bf16[row][j] * v_f32[j]  (one wave per row) ----
__global__ void rowdot_bf16_kernel(const unsigned short* __restrict__ A,
                                   const float* __restrict__ v,
                                   float* __restrict__ out, int D) {
  long row = (long)blockIdx.x * 4 + (threadIdx.x >> 6);
  int lane = threadIdx.x & 63;
  const ushort4* ar = (const ushort4*)(A + row * D);
  const float4* vv = (const float4*)v;
  float s = 0.f;
  for (int j = lane; j < D / 4; j += 64) {
    ushort4 a = ar[j];
    float4 g = vv[j];
    s += b2f(a.x) * g.x + b2f(a.y) * g.y + b2f(a.z) * g.z + b2f(a.w) * g.w;
  }
#pragma unroll
  for (int o = 32; o > 0; o >>= 1) s += __shfl_xor(s, o, 64);
  if (lane == 0) out[row] = s;
}

// ---------------- async global->LDS 16B ----------------
DEVI void gll16(const void* g, void* l) {
  __builtin_amdgcn_global_load_lds(
      (const __attribute__((address_space(1))) unsigned int*)g,
      (__attribute__((address_space(3))) unsigned int*)l, 16, 0, 0);
}

// ---------------- generic NT GEMM: C = (A * B^T + colbias) * scale ----------------
// A [M][K] bf16 row-major, B [N][K] bf16 row-major, C [M][N]. BK=64.
// Tile = (WM*ACCM*16) rows x (WN*ACCN*16) cols; WM*WN waves (256 thr);
// per-wave (ACCM*16) x (ACCN*16); mfma 16x16x32 bf16, 2 sub-k per iter.
// LDS stripe [16][64] bf16 with per-16B-slot XOR swizzle (slot ^= row&7) on
// BOTH the global staging source column (gll16 dest linear, rule 21) and the
// ds_read address -> conflict-free (round-11 verified: BANK_CONFLICT = 0).
// Single-buffered: stage -> sync -> compute -> sync (round-11/14 proven).
// Tested-and-REJECTED variants (do not retry): WAVES_EU=5 (acc spill, r13:
// 1.45 GB scratch); dbuf 64KB LDS (r12: residency halved); fp32-A reg
// staging (r15: serialized load->cvt->ds_write chains, scores 110->410 us);
// 8-phase counted-vmcnt (r3/r6: never reproduced m201's overlap).
// BATCH_X: batch folded into blockIdx.x low 3 bits (XCD affinity for B-panel).
template<int OUT_BF16, int HAS_BIAS, int BATCH_X,
         int WM, int WN, int ACCM, int ACCN, int WAVES_EU>
__global__ __launch_bounds__(256, WAVES_EU) void gemm_nt_kernel(
    const unsigned short* __restrict__ A,
    const unsigned short* __restrict__ B,
    void* __restrict__ Cv,
    const float* __restrict__ bias,
    float scale, int M, int N, int K,
    long sA, long sB, long sC, long sBias) {
  constexpr int NW = WM * WN;        // waves per block (4)
  constexpr int SA = WM * ACCM;      // A 16-row stripes per tile
  constexpr int SB = WN * ACCN;      // B 16-row stripes per tile
  constexpr int CA2 = SA * 2 / NW;   // A gll16 issues per wave
  constexpr int CB2 = SB * 2 / NW;
  static_assert(CA2 * NW == SA * 2 && CB2 * NW == SB * 2, "issue divisibility");

  __shared__ unsigned short As[SA * 1024];  // stripe = 1024 ushorts = 2 KB
  __shared__ unsigned short Bs[SB * 1024];

  const int tid = threadIdx.x;
  const int lane = tid & 63;
  const int wid = tid >> 6;
  const int wm = wid / WN;
  const int wn = wid % WN;

  int bx = blockIdx.x;
  int b;
  if (BATCH_X) { b = bx & 7; bx >>= 3; } else { b = blockIdx.z; }
  const int n0 = bx * (SB * 16);
  const int m0 = blockIdx.y * (SA * 16);

  const unsigned short* Ab = A + (long)b * sA;
  const unsigned short* Bb = B + (long)b * sB;
  const float* biasb = HAS_BIAS ? bias + (long)b * sBias : nullptr;

  // staging: issue (j,i) covers rows j*16+i*8..+7 of a stripe, 64 K-cols.
  // lane -> row offset lane>>3, source col slot (lane&7)^(lane>>3) (x8 elems)
  const int r8 = lane >> 3;
  const int csw = ((lane & 7) ^ r8) * 8;  // pre-swizzled source col (bf16 elems)

  auto stage = [&](int k0) {
#pragma unroll
    for (int t = 0; t < CA2; ++t) {
      const int a = wid * CA2 + t, j = a >> 1, i = a & 1;
      gll16(Ab + (long)(m0 + j * 16 + i * 8 + r8) * K + k0 + csw,
            (void*)(As + j * 1024 + i * 512));
    }
#pragma unroll
    for (int t = 0; t < CB2; ++t) {
      const int a = wid * CB2 + t, j = a >> 1, i = a & 1;
      gll16(Bb + (long)(n0 + j * 16 + i * 8 + r8) * K + k0 + csw,
            (void*)(Bs + j * 1024 + i * 512));
    }
  };

  f32x4 acc[ACCM][ACCN];
#pragma unroll
  for (int m = 0; m < ACCM; ++m)
#pragma unroll
    for (int n = 0; n < ACCN; ++n) acc[m][n] = (f32x4){0.f, 0.f, 0.f, 0.f};

  const int lrow = lane & 15;     // fragment row within 16-row stripe
  const int x7 = lane & 7;        // row&7 for the read-side XOR
  const int g = lane >> 4;        // k-group 0..3
  const int so0 = ((g) ^ x7) * 8;       // sub-k 0 swizzled ushort offset
  const int so1 = ((4 + g) ^ x7) * 8;   // sub-k 1
  const int wmA = wm * ACCM * 16;
  const int wnB = wn * ACCN * 16;

  for (int k0 = 0; k0 < K; k0 += 64) {
    stage(k0);
    __syncthreads();

#pragma unroll
    for (int s = 0; s < 2; ++s) {
      const int so = s ? so1 : so0;
      bf16x8 af[ACCM], bfr[ACCN];
#pragma unroll
      for (int m = 0; m < ACCM; ++m)
        af[m] = *reinterpret_cast<const bf16x8*>(
            &As[(wmA + m * 16 + lrow) * 64 + so]);
#pragma unroll
      for (int n = 0; n < ACCN; ++n)
        bfr[n] = *reinterpret_cast<const bf16x8*>(
            &Bs[(wnB + n * 16 + lrow) * 64 + so]);
#pragma unroll
      for (int m = 0; m < ACCM; ++m)
#pragma unroll
        for (int n = 0; n < ACCN; ++n)
          acc[m][n] = __builtin_amdgcn_mfma_f32_16x16x32_bf16(af[m], bfr[n], acc[m][n], 0, 0, 0);
    }

    __syncthreads();
  }

  const int crow = (lane >> 4) * 4;
  const int ccol = lane & 15;
#pragma unroll
  for (int m = 0; m < ACCM; ++m) {
#pragma unroll
    for (int n = 0; n < ACCN; ++n) {
      const int gc = n0 + wn * ACCN * 16 + n * 16 + ccol;
      float bv = HAS_BIAS ? biasb[gc] : 0.f;
#pragma unroll
      for (int r = 0; r < 4; ++r) {
        const int gr = m0 + wm * ACCM * 16 + m * 16 + crow + r;
        float v = (acc[m][n][r] + bv) * scale;
        long off = (long)b * sC + (long)gr * N + gc;
        if (OUT_BF16)
          ((unsigned short*)Cv)[off] = f2b(v);
        else
          ((float*)Cv)[off] = v;
      }
    }
  }
}

// ---------------- row softmax over P=576, fp32 in -> bf16 out ----------------
__global__ void softmax_kernel(const float* __restrict__ s,
                               unsigned short* __restrict__ attn) {
  const int P = 576;
  long row = (long)blockIdx.x * 4 + (threadIdx.x >> 6);
  int lane = threadIdx.x & 63;
  const float* sr = s + row * P;
  unsigned short* ar = attn + row * P;
  float v[9];
  float mx = -3.0e38f;
#pragma unroll
  for (int j = 0; j < 9; ++j) {
    v[j] = sr[j * 64 + lane];
    mx = fmaxf(mx, v[j]);
  }
#pragma unroll
  for (int o = 32; o > 0; o >>= 1) mx = fmaxf(mx, __shfl_xor(mx, o, 64));
  float sum = 0.f;
#pragma unroll
  for (int j = 0; j < 9; ++j) {
    v[j] = __expf(v[j] - mx);
    sum += v[j];
  }
#pragma unroll
  for (int o = 32; o > 0; o >>= 1) sum += __shfl_xor(sum, o, 64);
  float inv = 1.0f / sum;
#pragma unroll
  for (int j = 0; j < 9; ++j) ar[j * 64 + lane] = f2b(v[j] * inv);
}

extern "C" void kernel_launch(void* const* d_in, const int* in_sizes, int n_in,
                              void* d_out, int out_size, void* d_ws, size_t ws_size,
                              hipStream_t stream) {
  const float* text = (const float*)d_in[0];
  const float* feat = (const float*)d_in[1];
  const float* Wq = (const float*)d_in[2];
  const float* bq = (const float*)d_in[3];
  const float* Wk = (const float*)d_in[4];
  const float* bk = (const float*)d_in[5];
  (void)bk;  // bk's contribution to scores is constant over p -> softmax-invariant

  const int B = 8, T = 2048, P = 576, D = 4096;
  const long nText = (long)B * T * D;  // 67,108,864

  char* ws = (char*)d_ws;
  unsigned short* text_b = (unsigned short*)(ws);              // 134,217,728
  unsigned short* feat_b = (unsigned short*)(ws + 134217728);  //  37,748,736
  unsigned short* fT_b   = (unsigned short*)(ws + 171966464);  //  37,748,736
  unsigned short* WqT_b  = (unsigned short*)(ws + 209715200);  //  33,554,432
  unsigned short* WkT_b  = (unsigned short*)(ws + 243269632);  //  33,554,432
  unsigned short* attn_b = (unsigned short*)(ws + 276824064);  //  18,874,368
  float* u               = (float*)(ws + 295698432);           //      16,384
  float* c               = (float*)(ws + 295714816);           //      18,432
  float* scores          = (float*)(ws + 209715200);           // alias over WqT/WkT (dead after W2T)
  unsigned short* W2T_b  = (unsigned short*)d_out;                     // head of d_out
  unsigned short* KW_b   = (unsigned short*)((char*)d_out + 67108864); // +64 MB

  dim3 blk(256);
  cvt_kernel<<<4096, blk, 0, stream>>>(text, text_b, nText / 4);
  feat_cvt_tr_kernel<<<dim3(D / 32, P / 32, B), blk, 0, stream>>>(feat, feat_b, fT_b, P, D);
  wtr2_kernel<<<dim3(D / 32, D / 32, 2), blk, 0, stream>>>(Wq, Wk, WqT_b, WkT_b, D);
  // bias pre-pass (bf16 row-dots): u[y] = WkT[y,:].bq ; c[bp] = feat_b[bp,:].u
  rowdot_bf16_kernel<<<D / 4, blk, 0, stream>>>(WkT_b, bq, u, D);
  rowdot_bf16_kernel<<<(B * P) / 4, blk, 0, stream>>>(feat_b, u, c, D);

  // W2T[x][y] = sum_d Wq[d,x] Wk[d,y] : 128x128, BK=64 (round-11/14 proven)
  gemm_nt_kernel<1, 0, 0, 2, 2, 4, 4, 4><<<dim3(32, 32, 1), blk, 0, stream>>>(
      WqT_b, WkT_b, W2T_b, nullptr, 1.0f, D, D, D, 0, 0, 0, 0);
  // KW[bp][x] = sum_y feat[bp,y] W2T[x,y] : 128x128, BK=64
  gemm_nt_kernel<1, 0, 0, 2, 2, 4, 4, 4><<<dim3(32, 36, 1), blk, 0, stream>>>(
      feat_b, W2T_b, KW_b, nullptr, 1.0f, B * P, D, D, 0, 0, 0, 0);
  // scores[b][t][p] = (text[b,t,:].KW[b,p,:] + c[b,p]) / 64 : 256x64 tiles,
  // exact N fit, batch->XCD
  gemm_nt_kernel<0, 1, 1, 2, 2, 8, 2, 4><<<dim3(72, 8), blk, 0, stream>>>(
      text_b, KW_b, scores, c, 1.0f / 64.0f, T, P, D,
      (long)T * D, (long)P * D, (long)T * P, P);
  softmax_kernel<<<(B * T) / 4, blk, 0, stream>>>(scores, attn_b);
  // attended = attn * featT^T : 128x128 tiles, K=576, batch->XCD
  gemm_nt_kernel<0, 0, 1, 2, 2, 4, 4, 4><<<dim3(256, 16), blk, 0, stream>>>(
      attn_b, fT_b, (float*)d_out, nullptr, 1.0f, T, D, P,
      (long)T * P, (long)D * P, (long)T * D, 0);
}